// Round 4
// baseline (99.632 us; speedup 1.0000x reference)
//
#include <hip/hip_runtime.h>
#include <hip/hip_bf16.h>

typedef unsigned char u8;
typedef signed char i8;
typedef __attribute__((ext_vector_type(4))) int i32x4;

#define AS1 __attribute__((address_space(1)))
#define AS3 __attribute__((address_space(3)))

__device__ __forceinline__ void gload_lds16(const void* g, void* l) {
    __builtin_amdgcn_global_load_lds((const AS1 void*)g, (AS3 void*)l, 16, 0, 0);
}

// ------------- transpose [B, IN, T] f32 -> [T, B, IN] i8 (0/1) ---------------
__global__ void transpose_x2(const float* __restrict__ X, i8* __restrict__ Xb,
                             int B, int IN, int T) {
    __shared__ float tile[128][33];          // [i_loc][t_loc]
    const int t0 = blockIdx.x * 32, i0 = blockIdx.y * 128, b = blockIdx.z;
    const int tx = threadIdx.x & 31, ty = threadIdx.x >> 5;
    const float* src = X + (size_t)b * IN * T;
#pragma unroll
    for (int r = 0; r < 16; ++r) {
        int i = ty + r * 8;
        tile[i][tx] = src[(size_t)(i0 + i) * T + t0 + tx];
    }
    __syncthreads();
    const int cx = threadIdx.x & 31;         // which 4-byte chunk of 128 i's
    const int tl0 = threadIdx.x >> 5;
#pragma unroll
    for (int r = 0; r < 4; ++r) {
        int tl = tl0 + r * 8;                // t within tile
        uchar4 pk;
        pk.x = (tile[cx * 4 + 0][tl] != 0.f) ? 1 : 0;
        pk.y = (tile[cx * 4 + 1][tl] != 0.f) ? 1 : 0;
        pk.z = (tile[cx * 4 + 2][tl] != 0.f) ? 1 : 0;
        pk.w = (tile[cx * 4 + 3][tl] != 0.f) ? 1 : 0;
        *(uchar4*)&Xb[(size_t)(t0 + tl) * B * IN + (size_t)b * IN + i0 + cx * 4] = pk;
    }
}

// ------------- quantize both W: w -> i8( round_half_even(w/2) ), float4 ------
__global__ void quant_both(const float4* __restrict__ W1, const float4* __restrict__ W2,
                           char4* __restrict__ W1q, char4* __restrict__ W2q,
                           int n1v, int n2v) {
    int i = blockIdx.x * 256 + threadIdx.x;
    if (i < n1v) {
        float4 w = W1[i];
        char4 q;
        q.x = (i8)(int)rintf(w.x * 0.5f);
        q.y = (i8)(int)rintf(w.y * 0.5f);
        q.z = (i8)(int)rintf(w.z * 0.5f);
        q.w = (i8)(int)rintf(w.w * 0.5f);
        W1q[i] = q;
    } else if (i < n1v + n2v) {
        int j = i - n1v;
        float4 w = W2[j];
        char4 q;
        q.x = (i8)(int)rintf(w.x * 0.5f);
        q.y = (i8)(int)rintf(w.y * 0.5f);
        q.z = (i8)(int)rintf(w.z * 0.5f);
        q.w = (i8)(int)rintf(w.w * 0.5f);
        W2q[j] = q;
    }
}

// ------------- i8 GEMM, 2-phase dbuf: C = 2 * (A[M,K] . Bt[N,K]^T) -----------
// 128x128 tile, BK=128, 4 waves (2x2 of 64x64), mfma_i32_16x16x64_i8.
// Double-buffered LDS (64 KB): STAGE(t+1) issued BEFORE compute(t); ONE
// __syncthreads per iter (implicit vmcnt/lgkm drain before s_barrier).
template <int WRITE_I16>
__global__ __launch_bounds__(256, 2) void gemm_i8(
        const i8* __restrict__ A, const i8* __restrict__ Bt,
        void* __restrict__ Cv, int M, int N, int K, int nbx) {
    __shared__ __align__(16) i8 lA[2][128 * 128];
    __shared__ __align__(16) i8 lB[2][128 * 128];
    const int nwg = gridDim.x;
    const int cpx = nwg >> 3;                       // nwg % 8 == 0 by launch
    const int wg  = (blockIdx.x & 7) * cpx + (blockIdx.x >> 3);
    const int bx = wg % nbx, by = wg / nbx;

    const int tid  = threadIdx.x;
    const int lane = tid & 63;
    const int wave = tid >> 6;
    const int wm = wave >> 1, wn = wave & 1;
    const int m0 = by * 128;
    const int n0 = bx * 128;
    const int l15 = lane & 15;
    const int l4  = lane >> 4;

    i32x4 acc[4][4] = {};
    const int flatT = tid * 16;                     // 16 B per lane per issue

    // stage K-tile k0 into buffer `buf`
    auto STAGE = [&](int buf, int k0) {
#pragma unroll
        for (int q = 0; q < 4; ++q) {
            int fl = q * 4096 + flatT;
            int r = fl >> 7, c = fl & 127;
            gload_lds16(A + (size_t)(m0 + r) * K + k0 + c, &lA[buf][fl]);
        }
#pragma unroll
        for (int q = 0; q < 4; ++q) {
            int fl = q * 4096 + flatT;
            int r = fl >> 7, c = fl & 127;
            gload_lds16(Bt + (size_t)(n0 + r) * K + k0 + c, &lB[buf][fl]);
        }
    };

    STAGE(0, 0);
    __syncthreads();                                // drains vmcnt, tile 0 ready
    int cur = 0;

    for (int k0 = 0; k0 < K; k0 += 128) {
        if (k0 + 128 < K) STAGE(cur ^ 1, k0 + 128); // prefetch next tile
#pragma unroll
        for (int kk = 0; kk < 2; ++kk) {
            i32x4 af[4], bf[4];
#pragma unroll
            for (int mf = 0; mf < 4; ++mf)
                af[mf] = *(const i32x4*)&lA[cur][(wm * 64 + mf * 16 + l15) * 128 + kk * 64 + l4 * 16];
#pragma unroll
            for (int nf = 0; nf < 4; ++nf)
                bf[nf] = *(const i32x4*)&lB[cur][(wn * 64 + nf * 16 + l15) * 128 + kk * 64 + l4 * 16];
#pragma unroll
            for (int mf = 0; mf < 4; ++mf)
#pragma unroll
                for (int nf = 0; nf < 4; ++nf)
                    acc[mf][nf] = __builtin_amdgcn_mfma_i32_16x16x64_i8(
                        af[mf], bf[nf], acc[mf][nf], 0, 0, 0);
        }
        __syncthreads();                            // next tile landed; readers done
        cur ^= 1;
    }

#pragma unroll
    for (int mf = 0; mf < 4; ++mf)
#pragma unroll
        for (int nf = 0; nf < 4; ++nf) {
            int col = n0 + wn * 64 + nf * 16 + l15;
#pragma unroll
            for (int j = 0; j < 4; ++j) {
                int row = m0 + wm * 64 + mf * 16 + l4 * 4 + j;
                int v2 = acc[mf][nf][j] * 2;        // undo w/2 scaling, exact
                if (WRITE_I16) ((short*)Cv)[(size_t)row * N + col] = (short)v2;
                else           ((float*)Cv)[(size_t)row * N + col] = (float)v2;
            }
        }
}

// ------------- Loihi scan 1: H i16 -> pre-shifted i8 spikes, 32-deep dbuf ----
__global__ void scan1(const short* __restrict__ Hin, i8* __restrict__ Sout, int BH) {
    const int idx = blockIdx.x * 256 + threadIdx.x;
    const short* p = Hin + idx;
    i8* q = Sout + idx;
    q[0] = 0;                                       // t=0 row (delay shift)

    float a[32], b[32];
#pragma unroll
    for (int u = 0; u < 32; ++u) a[u] = (float)p[(size_t)u * BH];
    float I = 0.f, V = 0.f;

    for (int t = 0; t < 256; t += 64) {
#pragma unroll
        for (int u = 0; u < 32; ++u) b[u] = (float)p[(size_t)(t + 32 + u) * BH];
#pragma unroll
        for (int u = 0; u < 32; ++u) {
            I = floorf(I * 0.75f) + 64.f * a[u];
            V = floorf(V * 0.96875f) + I;
            float s = (V >= 5120.f) ? 1.f : 0.f;
            V *= (1.f - s);
            q[(size_t)(t + u + 1) * BH] = (i8)(s > 0.f ? 1 : 0);   // tt <= 224
        }
        if (t + 64 < 256) {
#pragma unroll
            for (int u = 0; u < 32; ++u) a[u] = (float)p[(size_t)(t + 64 + u) * BH];
        }
#pragma unroll
        for (int u = 0; u < 32; ++u) {
            I = floorf(I * 0.75f) + 64.f * b[u];
            V = floorf(V * 0.96875f) + I;
            float s = (V >= 5120.f) ? 1.f : 0.f;
            V *= (1.f - s);
            int tt = t + 32 + u + 1;
            if (tt < 256) q[(size_t)tt * BH] = (i8)(s > 0.f ? 1 : 0);
        }
    }
}

// ------------- Loihi scan 2 FUSED with output transpose ----------------------
// Input O [T, B*OUT] f32; output directly out [B,OUT,T] f32 (delay-shifted).
// Per 32-step batch: spikes -> LDS [tt_loc][neuron] -> coalesced [n][t] write.
__global__ void scan2_fused(const float* __restrict__ O, float* __restrict__ out,
                            int BO) {
    __shared__ float tileS[32][257];                // +1 pad: conflict-free cols
    const int tid = threadIdx.x;
    const int n0  = blockIdx.x * 256;               // first neuron of block
    const int idx = n0 + tid;
    const float* p = O + idx;

    float a[32], b[32];
#pragma unroll
    for (int u = 0; u < 32; ++u) a[u] = p[(size_t)u * BO];
    float I = 0.f, V = 0.f, carry = 0.f;            // carry: s from prev batch tail

    const int tq  = tid & 7;                        // t-quad 0..7
    const int lnb = tid >> 3;                       // 0..31

    auto flush = [&](int tt0) {
        __syncthreads();
#pragma unroll
        for (int g = 0; g < 8; ++g) {
            int ln = lnb + g * 32;                  // local neuron 0..255
            float4 v;
            v.x = tileS[tq * 4 + 0][ln];
            v.y = tileS[tq * 4 + 1][ln];
            v.z = tileS[tq * 4 + 2][ln];
            v.w = tileS[tq * 4 + 3][ln];
            *(float4*)&out[(size_t)(n0 + ln) * 256 + tt0 + tq * 4] = v;
        }
        __syncthreads();
    };

    for (int t = 0; t < 256; t += 64) {
        // ---- batch A: timesteps t .. t+31 -> output rows tt = t .. t+31
#pragma unroll
        for (int u = 0; u < 32; ++u) b[u] = p[(size_t)(t + 32 + u) * BO];
        tileS[0][tid] = carry;                      // tt = t (0 for t=0)
#pragma unroll
        for (int u = 0; u < 32; ++u) {
            I = floorf(I * 0.75f) + 64.f * a[u];
            V = floorf(V * 0.96875f) + I;
            float s = (V >= 5120.f) ? 1.f : 0.f;
            V *= (1.f - s);
            if (u < 31) tileS[u + 1][tid] = s; else carry = s;
        }
        flush(t);
        // ---- batch B: timesteps t+32 .. t+63 -> output rows tt = t+32 .. t+63
        if (t + 64 < 256) {
#pragma unroll
            for (int u = 0; u < 32; ++u) a[u] = p[(size_t)(t + 64 + u) * BO];
        }
        tileS[0][tid] = carry;
#pragma unroll
        for (int u = 0; u < 32; ++u) {
            I = floorf(I * 0.75f) + 64.f * b[u];
            V = floorf(V * 0.96875f) + I;
            float s = (V >= 5120.f) ? 1.f : 0.f;
            V *= (1.f - s);
            if (u < 31) tileS[u + 1][tid] = s; else carry = s;
        }
        flush(t + 32);                              // last batch: s_255 dropped
    }
}

extern "C" void kernel_launch(void* const* d_in, const int* in_sizes, int n_in,
                              void* d_out, int out_size, void* d_ws, size_t ws_size,
                              hipStream_t stream) {
    const int B = 32, IN = 1024, HID = 2048, OUT = 512, T = 256;
    const float* spikes = (const float*)d_in[0];
    const float* W1 = (const float*)d_in[1];
    const float* W2 = (const float*)d_in[2];
    float* out = (float*)d_out;

    char* ws = (char*)d_ws;
    size_t off = 0;
    auto alloc = [&](size_t bytes) -> void* {
        void* p = ws + off;
        off += (bytes + 255) & ~(size_t)255;
        return p;
    };
    i8*    Xb  = (i8*)   alloc((size_t)T * B * IN);         // [T,B,IN] i8 0/1
    i8*    W1q = (i8*)   alloc((size_t)HID * IN);           // [HID,IN] i8 = w/2
    i8*    W2q = (i8*)   alloc((size_t)OUT * HID);          // [OUT,HID] i8 = w/2
    short* H   = (short*)alloc((size_t)T * B * HID * 2);    // [T,B,HID] i16 exact
    i8*    S1  = (i8*)   alloc((size_t)T * B * HID);        // [T,B,HID] i8 (shifted)
    float* O   = (float*)alloc((size_t)T * B * OUT * 4);    // [T,B,OUT] f32 exact

    dim3 blk(256);
    transpose_x2<<<dim3(T / 32, IN / 128, B), blk, 0, stream>>>(spikes, Xb, B, IN, T);
    {
        int n1v = HID * IN / 4, n2v = OUT * HID / 4;
        quant_both<<<dim3((n1v + n2v + 255) / 256), blk, 0, stream>>>(
            (const float4*)W1, (const float4*)W2, (char4*)W1q, (char4*)W2q, n1v, n2v);
    }
    {   // GEMM1: [8192,1024]i8 x [2048,1024]i8^T -> H i16 ; 16x64=1024 wgs
        int nbx = HID / 128, nby = (T * B) / 128;
        gemm_i8<1><<<dim3(nbx * nby), blk, 0, stream>>>(Xb, W1q, H, T * B, HID, IN, nbx);
    }
    scan1<<<dim3(B * HID / 256), blk, 0, stream>>>(H, S1, B * HID);
    {   // GEMM2: [8192,2048]i8 x [512,2048]i8^T -> O f32 ; 4x64=256 wgs
        int nbx = OUT / 128, nby = (T * B) / 128;
        gemm_i8<0><<<dim3(nbx * nby), blk, 0, stream>>>(S1, W2q, O, T * B, OUT, HID, nbx);
    }
    scan2_fused<<<dim3(B * OUT / 256), blk, 0, stream>>>(O, out, B * OUT);
}

// Round 5
// 83.910 us; speedup vs baseline: 1.1874x; 1.1874x over previous
//
#include <hip/hip_runtime.h>
#include <hip/hip_bf16.h>

typedef unsigned char u8;
typedef signed char i8;
typedef __attribute__((ext_vector_type(4))) int i32x4;

#define AS1 __attribute__((address_space(1)))
#define AS3 __attribute__((address_space(3)))

__device__ __forceinline__ void gload_lds16(const void* g, void* l) {
    __builtin_amdgcn_global_load_lds((const AS1 void*)g, (AS3 void*)l, 16, 0, 0);
}

// ------------- transpose [B, IN, T] f32 -> [T, B, IN] i8 (0/1) ---------------
__global__ void transpose_x2(const float* __restrict__ X, i8* __restrict__ Xb,
                             int B, int IN, int T) {
    __shared__ float tile[128][33];          // [i_loc][t_loc]
    const int t0 = blockIdx.x * 32, i0 = blockIdx.y * 128, b = blockIdx.z;
    const int tx = threadIdx.x & 31, ty = threadIdx.x >> 5;
    const float* src = X + (size_t)b * IN * T;
#pragma unroll
    for (int r = 0; r < 16; ++r) {
        int i = ty + r * 8;
        tile[i][tx] = src[(size_t)(i0 + i) * T + t0 + tx];
    }
    __syncthreads();
    const int cx = threadIdx.x & 31;         // which 4-byte chunk of 128 i's
    const int tl0 = threadIdx.x >> 5;
#pragma unroll
    for (int r = 0; r < 4; ++r) {
        int tl = tl0 + r * 8;                // t within tile
        uchar4 pk;
        pk.x = (tile[cx * 4 + 0][tl] != 0.f) ? 1 : 0;
        pk.y = (tile[cx * 4 + 1][tl] != 0.f) ? 1 : 0;
        pk.z = (tile[cx * 4 + 2][tl] != 0.f) ? 1 : 0;
        pk.w = (tile[cx * 4 + 3][tl] != 0.f) ? 1 : 0;
        *(uchar4*)&Xb[(size_t)(t0 + tl) * B * IN + (size_t)b * IN + i0 + cx * 4] = pk;
    }
}

// ------------- quantize both W: w -> i8( round_half_even(w/2) ), float4 ------
__global__ void quant_both(const float4* __restrict__ W1, const float4* __restrict__ W2,
                           char4* __restrict__ W1q, char4* __restrict__ W2q,
                           int n1v, int n2v) {
    int i = blockIdx.x * 256 + threadIdx.x;
    if (i < n1v) {
        float4 w = W1[i];
        char4 q;
        q.x = (i8)(int)rintf(w.x * 0.5f);
        q.y = (i8)(int)rintf(w.y * 0.5f);
        q.z = (i8)(int)rintf(w.z * 0.5f);
        q.w = (i8)(int)rintf(w.w * 0.5f);
        W1q[i] = q;
    } else if (i < n1v + n2v) {
        int j = i - n1v;
        float4 w = W2[j];
        char4 q;
        q.x = (i8)(int)rintf(w.x * 0.5f);
        q.y = (i8)(int)rintf(w.y * 0.5f);
        q.z = (i8)(int)rintf(w.z * 0.5f);
        q.w = (i8)(int)rintf(w.w * 0.5f);
        W2q[j] = q;
    }
}

// ------------- i8 GEMM: C = 2 * (A[M,K] . Bt[N,K]^T), XOR-swizzled LDS -------
// 128x128 tile, BK=128 (128 B/row), 4 waves (2x2 of 64x64), mfma_i32_16x16x64.
// Bank-conflict fix (T2 for gload_lds, m201/m231 both-sides involution):
//   LDS dest stays LINEAR (gload_lds requirement); the 16B chunk index is
//   XOR-permuted on the GLOBAL source (chunk^=(row&7)) and the SAME XOR is
//   applied on the ds_read address. 16 rows -> 8 distinct chunk columns
//   -> 2 lanes/bank (free) instead of 16-way.
// DBUF=0: single buffer (32 KB), 2 barriers/iter, 3 blocks/CU (TLP hides drain).
// DBUF=1: double buffer (64 KB), prefetch + 1 barrier/iter (for 1-block/CU grids).
template <int WRITE_I16, int DBUF>
__global__ __launch_bounds__(256, DBUF ? 2 : 3) void gemm_i8(
        const i8* __restrict__ A, const i8* __restrict__ Bt,
        void* __restrict__ Cv, int M, int N, int K, int nbx) {
    __shared__ __align__(16) i8 lA[(DBUF ? 2 : 1) * 128 * 128];
    __shared__ __align__(16) i8 lB[(DBUF ? 2 : 1) * 128 * 128];
    const int nwg = gridDim.x;
    const int cpx = nwg >> 3;                       // nwg % 8 == 0 by launch
    const int wg  = (blockIdx.x & 7) * cpx + (blockIdx.x >> 3);
    const int bx = wg % nbx, by = wg / nbx;

    const int tid  = threadIdx.x;
    const int lane = tid & 63;
    const int wave = tid >> 6;
    const int wm = wave >> 1, wn = wave & 1;
    const int m0 = by * 128;
    const int n0 = bx * 128;
    const int l15 = lane & 15;
    const int l4  = lane >> 4;
    const int sw  = l15 & 7;                        // read-side XOR key

    i32x4 acc[4][4] = {};
    const int flatT = tid * 16;                     // linear LDS byte pos

    auto STAGE = [&](int buf, int k0) {
#pragma unroll
        for (int q = 0; q < 4; ++q) {
            int fl = q * 4096 + flatT;
            int r  = fl >> 7;
            int sc = ((fl >> 4) & 7) ^ (r & 7);     // pre-swizzled source chunk
            gload_lds16(A + (size_t)(m0 + r) * K + k0 + sc * 16,
                        &lA[buf * 16384 + fl]);
        }
#pragma unroll
        for (int q = 0; q < 4; ++q) {
            int fl = q * 4096 + flatT;
            int r  = fl >> 7;
            int sc = ((fl >> 4) & 7) ^ (r & 7);
            gload_lds16(Bt + (size_t)(n0 + r) * K + k0 + sc * 16,
                        &lB[buf * 16384 + fl]);
        }
    };

    auto COMPUTE = [&](int buf) {
#pragma unroll
        for (int kk = 0; kk < 2; ++kk) {
            i32x4 af[4], bf[4];
#pragma unroll
            for (int mf = 0; mf < 4; ++mf)
                af[mf] = *(const i32x4*)&lA[buf * 16384 +
                    (wm * 64 + mf * 16 + l15) * 128 + ((kk * 4 + l4) ^ sw) * 16];
#pragma unroll
            for (int nf = 0; nf < 4; ++nf)
                bf[nf] = *(const i32x4*)&lB[buf * 16384 +
                    (wn * 64 + nf * 16 + l15) * 128 + ((kk * 4 + l4) ^ sw) * 16];
#pragma unroll
            for (int mf = 0; mf < 4; ++mf)
#pragma unroll
                for (int nf = 0; nf < 4; ++nf)
                    acc[mf][nf] = __builtin_amdgcn_mfma_i32_16x16x64_i8(
                        af[mf], bf[nf], acc[mf][nf], 0, 0, 0);
        }
    };

    if (DBUF) {
        STAGE(0, 0);
        __syncthreads();                            // tile 0 landed
        int cur = 0;
        for (int k0 = 0; k0 < K; k0 += 128) {
            if (k0 + 128 < K) STAGE(cur ^ 1, k0 + 128);
            COMPUTE(cur);
            __syncthreads();                        // prefetch landed, readers done
            cur ^= 1;
        }
    } else {
        for (int k0 = 0; k0 < K; k0 += 128) {
            __syncthreads();                        // prev readers done
            STAGE(0, k0);
            __syncthreads();                        // tile landed
            COMPUTE(0);
        }
    }

#pragma unroll
    for (int mf = 0; mf < 4; ++mf)
#pragma unroll
        for (int nf = 0; nf < 4; ++nf) {
            int col = n0 + wn * 64 + nf * 16 + l15;
#pragma unroll
            for (int j = 0; j < 4; ++j) {
                int row = m0 + wm * 64 + mf * 16 + l4 * 4 + j;
                int v2 = acc[mf][nf][j] * 2;        // undo w/2 scaling, exact
                if (WRITE_I16) ((short*)Cv)[(size_t)row * N + col] = (short)v2;
                else           ((float*)Cv)[(size_t)row * N + col] = (float)v2;
            }
        }
}

// ------------- Loihi scan 1: H i16 -> pre-shifted i8 spikes, 32-deep dbuf ----
__global__ void scan1(const short* __restrict__ Hin, i8* __restrict__ Sout, int BH) {
    const int idx = blockIdx.x * 256 + threadIdx.x;
    const short* p = Hin + idx;
    i8* q = Sout + idx;
    q[0] = 0;                                       // t=0 row (delay shift)

    float a[32], b[32];
#pragma unroll
    for (int u = 0; u < 32; ++u) a[u] = (float)p[(size_t)u * BH];
    float I = 0.f, V = 0.f;

    for (int t = 0; t < 256; t += 64) {
#pragma unroll
        for (int u = 0; u < 32; ++u) b[u] = (float)p[(size_t)(t + 32 + u) * BH];
#pragma unroll
        for (int u = 0; u < 32; ++u) {
            I = floorf(I * 0.75f) + 64.f * a[u];
            V = floorf(V * 0.96875f) + I;
            float s = (V >= 5120.f) ? 1.f : 0.f;
            V *= (1.f - s);
            q[(size_t)(t + u + 1) * BH] = (i8)(s > 0.f ? 1 : 0);   // tt <= 224
        }
        if (t + 64 < 256) {
#pragma unroll
            for (int u = 0; u < 32; ++u) a[u] = (float)p[(size_t)(t + 64 + u) * BH];
        }
#pragma unroll
        for (int u = 0; u < 32; ++u) {
            I = floorf(I * 0.75f) + 64.f * b[u];
            V = floorf(V * 0.96875f) + I;
            float s = (V >= 5120.f) ? 1.f : 0.f;
            V *= (1.f - s);
            int tt = t + 32 + u + 1;
            if (tt < 256) q[(size_t)tt * BH] = (i8)(s > 0.f ? 1 : 0);
        }
    }
}

// ------------- Loihi scan 2 FUSED with output transpose ----------------------
__global__ void scan2_fused(const float* __restrict__ O, float* __restrict__ out,
                            int BO) {
    __shared__ float tileS[32][257];                // +1 pad: conflict-free cols
    const int tid = threadIdx.x;
    const int n0  = blockIdx.x * 256;               // first neuron of block
    const int idx = n0 + tid;
    const float* p = O + idx;

    float a[32], b[32];
#pragma unroll
    for (int u = 0; u < 32; ++u) a[u] = p[(size_t)u * BO];
    float I = 0.f, V = 0.f, carry = 0.f;            // carry: prev batch tail spike

    const int tq  = tid & 7;                        // t-quad 0..7
    const int lnb = tid >> 3;                       // 0..31

    auto flush = [&](int tt0) {
        __syncthreads();
#pragma unroll
        for (int g = 0; g < 8; ++g) {
            int ln = lnb + g * 32;                  // local neuron 0..255
            float4 v;
            v.x = tileS[tq * 4 + 0][ln];
            v.y = tileS[tq * 4 + 1][ln];
            v.z = tileS[tq * 4 + 2][ln];
            v.w = tileS[tq * 4 + 3][ln];
            *(float4*)&out[(size_t)(n0 + ln) * 256 + tt0 + tq * 4] = v;
        }
        __syncthreads();
    };

    for (int t = 0; t < 256; t += 64) {
#pragma unroll
        for (int u = 0; u < 32; ++u) b[u] = p[(size_t)(t + 32 + u) * BO];
        tileS[0][tid] = carry;                      // tt = t (0 for t=0)
#pragma unroll
        for (int u = 0; u < 32; ++u) {
            I = floorf(I * 0.75f) + 64.f * a[u];
            V = floorf(V * 0.96875f) + I;
            float s = (V >= 5120.f) ? 1.f : 0.f;
            V *= (1.f - s);
            if (u < 31) tileS[u + 1][tid] = s; else carry = s;
        }
        flush(t);
        if (t + 64 < 256) {
#pragma unroll
            for (int u = 0; u < 32; ++u) a[u] = p[(size_t)(t + 64 + u) * BO];
        }
        tileS[0][tid] = carry;
#pragma unroll
        for (int u = 0; u < 32; ++u) {
            I = floorf(I * 0.75f) + 64.f * b[u];
            V = floorf(V * 0.96875f) + I;
            float s = (V >= 5120.f) ? 1.f : 0.f;
            V *= (1.f - s);
            if (u < 31) tileS[u + 1][tid] = s; else carry = s;
        }
        flush(t + 32);                              // last batch: s_255 dropped
    }
}

extern "C" void kernel_launch(void* const* d_in, const int* in_sizes, int n_in,
                              void* d_out, int out_size, void* d_ws, size_t ws_size,
                              hipStream_t stream) {
    const int B = 32, IN = 1024, HID = 2048, OUT = 512, T = 256;
    const float* spikes = (const float*)d_in[0];
    const float* W1 = (const float*)d_in[1];
    const float* W2 = (const float*)d_in[2];
    float* out = (float*)d_out;

    char* ws = (char*)d_ws;
    size_t off = 0;
    auto alloc = [&](size_t bytes) -> void* {
        void* p = ws + off;
        off += (bytes + 255) & ~(size_t)255;
        return p;
    };
    i8*    Xb  = (i8*)   alloc((size_t)T * B * IN);         // [T,B,IN] i8 0/1
    i8*    W1q = (i8*)   alloc((size_t)HID * IN);           // [HID,IN] i8 = w/2
    i8*    W2q = (i8*)   alloc((size_t)OUT * HID);          // [OUT,HID] i8 = w/2
    short* H   = (short*)alloc((size_t)T * B * HID * 2);    // [T,B,HID] i16 exact
    i8*    S1  = (i8*)   alloc((size_t)T * B * HID);        // [T,B,HID] i8 (shifted)
    float* O   = (float*)alloc((size_t)T * B * OUT * 4);    // [T,B,OUT] f32 exact

    dim3 blk(256);
    transpose_x2<<<dim3(T / 32, IN / 128, B), blk, 0, stream>>>(spikes, Xb, B, IN, T);
    {
        int n1v = HID * IN / 4, n2v = OUT * HID / 4;
        quant_both<<<dim3((n1v + n2v + 255) / 256), blk, 0, stream>>>(
            (const float4*)W1, (const float4*)W2, (char4*)W1q, (char4*)W2q, n1v, n2v);
    }
    {   // GEMM1: 16x64=1024 wgs -> 4 grid-blocks/CU available: serial + 3 blk/CU
        int nbx = HID / 128, nby = (T * B) / 128;
        gemm_i8<1, 0><<<dim3(nbx * nby), blk, 0, stream>>>(Xb, W1q, H, T * B, HID, IN, nbx);
    }
    scan1<<<dim3(B * HID / 256), blk, 0, stream>>>(H, S1, B * HID);
    {   // GEMM2: 4x64=256 wgs = 1 block/CU -> dbuf for intra-block overlap
        int nbx = OUT / 128, nby = (T * B) / 128;
        gemm_i8<0, 1><<<dim3(nbx * nby), blk, 0, stream>>>(S1, W2q, O, T * B, OUT, HID, nbx);
    }
    scan2_fused<<<dim3(B * OUT / 256), blk, 0, stream>>>(O, out, B * OUT);
}

// Round 6
// 81.106 us; speedup vs baseline: 1.2284x; 1.0346x over previous
//
#include <hip/hip_runtime.h>

typedef unsigned char u8;
typedef signed char i8;
typedef unsigned int u32;
typedef __attribute__((ext_vector_type(4))) int i32x4;

#define AS1 __attribute__((address_space(1)))
#define AS3 __attribute__((address_space(3)))

__device__ __forceinline__ void gload_lds16(const void* g, void* l) {
    __builtin_amdgcn_global_load_lds((const AS1 void*)g, (AS3 void*)l, 16, 0, 0);
}

// ---------- transpose [B, IN, T] f32 -> [B, T, IN] i8 (0/1) ------------------
__global__ void transpose_x_bt(const float* __restrict__ X, i8* __restrict__ Xb,
                               int B, int IN, int T) {
    __shared__ float tile[128][33];          // [i_loc][t_loc]
    const int t0 = blockIdx.x * 32, i0 = blockIdx.y * 128, b = blockIdx.z;
    const int tx = threadIdx.x & 31, ty = threadIdx.x >> 5;
    const float* src = X + (size_t)b * IN * T;
#pragma unroll
    for (int r = 0; r < 16; ++r) {
        int i = ty + r * 8;
        tile[i][tx] = src[(size_t)(i0 + i) * T + t0 + tx];
    }
    __syncthreads();
    const int cx = threadIdx.x & 31;         // 4-i chunk within 128
    const int tl0 = threadIdx.x >> 5;
#pragma unroll
    for (int r = 0; r < 4; ++r) {
        int tl = tl0 + r * 8;
        uchar4 pk;
        pk.x = (tile[cx * 4 + 0][tl] != 0.f) ? 1 : 0;
        pk.y = (tile[cx * 4 + 1][tl] != 0.f) ? 1 : 0;
        pk.z = (tile[cx * 4 + 2][tl] != 0.f) ? 1 : 0;
        pk.w = (tile[cx * 4 + 3][tl] != 0.f) ? 1 : 0;
        *(uchar4*)&Xb[((size_t)b * T + t0 + tl) * IN + i0 + cx * 4] = pk;
    }
}

// ---------- quantize both W: w -> i8( round_half_even(w/2) ), float4 ---------
__global__ void quant_both(const float4* __restrict__ W1, const float4* __restrict__ W2,
                           char4* __restrict__ W1q, char4* __restrict__ W2q,
                           int n1v, int n2v) {
    int i = blockIdx.x * 256 + threadIdx.x;
    if (i < n1v) {
        float4 w = W1[i];
        char4 q;
        q.x = (i8)(int)rintf(w.x * 0.5f);
        q.y = (i8)(int)rintf(w.y * 0.5f);
        q.z = (i8)(int)rintf(w.z * 0.5f);
        q.w = (i8)(int)rintf(w.w * 0.5f);
        W1q[i] = q;
    } else if (i < n1v + n2v) {
        int j = i - n1v;
        float4 w = W2[j];
        char4 q;
        q.x = (i8)(int)rintf(w.x * 0.5f);
        q.y = (i8)(int)rintf(w.y * 0.5f);
        q.z = (i8)(int)rintf(w.z * 0.5f);
        q.w = (i8)(int)rintf(w.w * 0.5f);
        W2q[j] = q;
    }
}

// ---------- FUSED GEMM1 + Loihi scan1 ----------------------------------------
// A = Xb [B*T, 1024] i8 (b-major rows), Bt = W1q [2048, 1024] i8.
// Block: 256x64 output tile = ALL 256 timesteps of batch `by` x 64 neurons.
// Phase 1: i8 MFMA GEMM (BK=128, XOR-swizzled staging, 4 waves of 64x64 rows).
// Phase 2: acc*2 -> LDS hT[n][t] i16 (swizzled 4-t chunks, b64 writes).
// Phase 3: wave 0 scans 64 neurons over 256 t (8-deep pipelined LDS reads),
//          packing spikes into per-neuron 256-bit masks in LDS.
// Phase 4: all threads write delay-shifted S1 [B*T, 2048] i8 dwords, coalesced.
__global__ __launch_bounds__(256, 3) void gemm1_scan1(
        const i8* __restrict__ A, const i8* __restrict__ Bt,
        i8* __restrict__ S1, int K) {
    __shared__ __align__(16) i8 lds[40960];
    i8*    lA   = lds;                        // 256x128 staging  (32 KB)
    i8*    lB   = lds + 32768;                // 64x128 staging   (8 KB)
    short* hT   = (short*)lds;                // [64 n][256 t] i16 (aliases lA)
    u32*   bits = (u32*)(lds + 32768);        // [8 w][64 n]       (aliases lB)

    const int nwg = gridDim.x;                // 1024, %8==0
    const int cpx = nwg >> 3;
    const int wg  = (blockIdx.x & 7) * cpx + (blockIdx.x >> 3);
    const int bx = wg & 31;                   // neuron tile (32 of 64)
    const int by = wg >> 5;                   // batch element (32)
    const int n0 = bx * 64;
    const int m0 = by * 256;

    const int tid  = threadIdx.x;
    const int lane = tid & 63;
    const int w    = tid >> 6;                // wave = M-quadrant (64 rows)
    const int l15 = lane & 15;
    const int l4  = lane >> 4;
    const int sw  = l15 & 7;

    i32x4 acc[4][4] = {};
    const int flatT = tid * 16;

    for (int k0 = 0; k0 < K; k0 += 128) {
        __syncthreads();
#pragma unroll
        for (int q = 0; q < 8; ++q) {         // A: 32 KB
            int fl = q * 4096 + flatT;
            int r  = fl >> 7;
            int sc = ((fl >> 4) & 7) ^ (r & 7);
            gload_lds16(A + (size_t)(m0 + r) * K + k0 + sc * 16, &lA[fl]);
        }
#pragma unroll
        for (int q = 0; q < 2; ++q) {         // B: 8 KB
            int fl = q * 4096 + flatT;
            int r  = fl >> 7;
            int sc = ((fl >> 4) & 7) ^ (r & 7);
            gload_lds16(Bt + (size_t)(n0 + r) * K + k0 + sc * 16, &lB[fl]);
        }
        __syncthreads();
#pragma unroll
        for (int kk = 0; kk < 2; ++kk) {
            i32x4 af[4], bf[4];
#pragma unroll
            for (int mf = 0; mf < 4; ++mf)
                af[mf] = *(const i32x4*)&lA[(w * 64 + mf * 16 + l15) * 128 +
                                            ((kk * 4 + l4) ^ sw) * 16];
#pragma unroll
            for (int nf = 0; nf < 4; ++nf)
                bf[nf] = *(const i32x4*)&lB[(nf * 16 + l15) * 128 +
                                            ((kk * 4 + l4) ^ sw) * 16];
#pragma unroll
            for (int mf = 0; mf < 4; ++mf)
#pragma unroll
                for (int nf = 0; nf < 4; ++nf)
                    acc[mf][nf] = __builtin_amdgcn_mfma_i32_16x16x64_i8(
                        af[mf], bf[nf], acc[mf][nf], 0, 0, 0);
        }
    }
    __syncthreads();                          // staging LDS dead; reuse as hT

    // ---- phase 2: acc -> hT[n][t] i16, swizzled b64 chunk writes ------------
#pragma unroll
    for (int mf = 0; mf < 4; ++mf)
#pragma unroll
        for (int nf = 0; nf < 4; ++nf) {
            int n = nf * 16 + l15;
            int c = w * 16 + mf * 4 + l4;     // t-chunk (4 t's)
            int h0 = acc[mf][nf][0] * 2, h1 = acc[mf][nf][1] * 2;
            int h2 = acc[mf][nf][2] * 2, h3 = acc[mf][nf][3] * 2;
            int2 pk;
            pk.x = (h0 & 0xffff) | (h1 << 16);
            pk.y = (h2 & 0xffff) | (h3 << 16);
            *(int2*)((char*)hT + n * 512 + ((c ^ (n & 15)) << 3)) = pk;
        }
    __syncthreads();

    // ---- phase 3: wave 0 scans 64 neurons ----------------------------------
    if (w == 0) {
        const int n = lane;
        const int nx = n & 15;
        const char* hrow = (char*)hT + n * 512;
        int2 ra[4], rb[4];
#pragma unroll
        for (int q = 0; q < 4; ++q)
            ra[q] = *(const int2*)(hrow + ((q ^ nx) << 3));
        u32 bw[8] = {0, 0, 0, 0, 0, 0, 0, 0};
        float I = 0.f, V = 0.f;
#pragma unroll
        for (int p = 0; p < 16; ++p) {        // 16 phases x 16 t
            if (p < 15) {
#pragma unroll
                for (int q = 0; q < 4; ++q) {
                    int2 v = *(const int2*)(hrow + ((((p + 1) * 4 + q) ^ nx) << 3));
                    if (p & 1) ra[q] = v; else rb[q] = v;
                }
            }
#pragma unroll
            for (int q = 0; q < 4; ++q) {
                int2 hh = (p & 1) ? rb[q] : ra[q];
#pragma unroll
                for (int j = 0; j < 4; ++j) {
                    int t = p * 16 + q * 4 + j;
                    short hv = (j == 0) ? (short)hh.x
                             : (j == 1) ? (short)(hh.x >> 16)
                             : (j == 2) ? (short)hh.y
                                        : (short)(hh.y >> 16);
                    I = floorf(I * 0.75f) + 64.f * (float)hv;
                    V = floorf(V * 0.96875f) + I;
                    if (V >= 5120.f) { bw[t >> 5] |= (1u << (t & 31)); V = 0.f; }
                }
            }
        }
#pragma unroll
        for (int wi = 0; wi < 8; ++wi) bits[wi * 64 + n] = bw[wi];
    }
    __syncthreads();

    // ---- phase 4: delay-shifted spike write, coalesced dwords ---------------
#pragma unroll
    for (int rep = 0; rep < 16; ++rep) {
        int d   = rep * 256 + tid;            // 0..4095 = 256 rows x 16 dwords
        int tt  = d >> 4;                     // output timestep row
        int ndq = d & 15;                     // dword (4 neurons) within 64
        u32 outw = 0;
        if (tt > 0) {
            int tb = tt - 1, wi = tb >> 5, sh = tb & 31;
            outw =  ((bits[wi * 64 + ndq * 4 + 0] >> sh) & 1)
                 | (((bits[wi * 64 + ndq * 4 + 1] >> sh) & 1) << 8)
                 | (((bits[wi * 64 + ndq * 4 + 2] >> sh) & 1) << 16)
                 | (((bits[wi * 64 + ndq * 4 + 3] >> sh) & 1) << 24);
        }
        *(u32*)&S1[(size_t)(m0 + tt) * 2048 + n0 + ndq * 4] = outw;
    }
}

// ---------- GEMM2: O f32 = 2 * (S1[M,K]i8 . W2q[N,K]i8^T), dbuf --------------
__global__ __launch_bounds__(256, 2) void gemm2_i8(
        const i8* __restrict__ A, const i8* __restrict__ Bt,
        float* __restrict__ C, int M, int N, int K, int nbx) {
    __shared__ __align__(16) i8 lA[2 * 128 * 128];
    __shared__ __align__(16) i8 lB[2 * 128 * 128];
    const int nwg = gridDim.x;
    const int cpx = nwg >> 3;
    const int wg  = (blockIdx.x & 7) * cpx + (blockIdx.x >> 3);
    const int bx = wg % nbx, by = wg / nbx;

    const int tid  = threadIdx.x;
    const int lane = tid & 63;
    const int wave = tid >> 6;
    const int wm = wave >> 1, wn = wave & 1;
    const int m0 = by * 128;
    const int n0 = bx * 128;
    const int l15 = lane & 15;
    const int l4  = lane >> 4;
    const int sw  = l15 & 7;

    i32x4 acc[4][4] = {};
    const int flatT = tid * 16;

    auto STAGE = [&](int buf, int k0) {
#pragma unroll
        for (int q = 0; q < 4; ++q) {
            int fl = q * 4096 + flatT;
            int r  = fl >> 7;
            int sc = ((fl >> 4) & 7) ^ (r & 7);
            gload_lds16(A + (size_t)(m0 + r) * K + k0 + sc * 16, &lA[buf * 16384 + fl]);
        }
#pragma unroll
        for (int q = 0; q < 4; ++q) {
            int fl = q * 4096 + flatT;
            int r  = fl >> 7;
            int sc = ((fl >> 4) & 7) ^ (r & 7);
            gload_lds16(Bt + (size_t)(n0 + r) * K + k0 + sc * 16, &lB[buf * 16384 + fl]);
        }
    };

    STAGE(0, 0);
    __syncthreads();
    int cur = 0;
    for (int k0 = 0; k0 < K; k0 += 128) {
        if (k0 + 128 < K) STAGE(cur ^ 1, k0 + 128);
#pragma unroll
        for (int kk = 0; kk < 2; ++kk) {
            i32x4 af[4], bf[4];
#pragma unroll
            for (int mf = 0; mf < 4; ++mf)
                af[mf] = *(const i32x4*)&lA[cur * 16384 +
                    (wm * 64 + mf * 16 + l15) * 128 + ((kk * 4 + l4) ^ sw) * 16];
#pragma unroll
            for (int nf = 0; nf < 4; ++nf)
                bf[nf] = *(const i32x4*)&lB[cur * 16384 +
                    (wn * 64 + nf * 16 + l15) * 128 + ((kk * 4 + l4) ^ sw) * 16];
#pragma unroll
            for (int mf = 0; mf < 4; ++mf)
#pragma unroll
                for (int nf = 0; nf < 4; ++nf)
                    acc[mf][nf] = __builtin_amdgcn_mfma_i32_16x16x64_i8(
                        af[mf], bf[nf], acc[mf][nf], 0, 0, 0);
        }
        __syncthreads();
        cur ^= 1;
    }
#pragma unroll
    for (int mf = 0; mf < 4; ++mf)
#pragma unroll
        for (int nf = 0; nf < 4; ++nf) {
            int col = n0 + wn * 64 + nf * 16 + l15;
#pragma unroll
            for (int j = 0; j < 4; ++j) {
                int row = m0 + wm * 64 + mf * 16 + l4 * 4 + j;
                C[(size_t)row * N + col] = (float)(acc[mf][nf][j] * 2);
            }
        }
}

// ---------- Loihi scan 2 FUSED with output transpose -------------------------
// O: [B*T, 512] f32, b-major rows; out: [B, OUT, T] f32 (delay-shifted).
__global__ void scan2_fused(const float* __restrict__ O, float* __restrict__ out) {
    __shared__ float tileS[32][257];
    const int tid = threadIdx.x;
    const int g0  = blockIdx.x * 256;               // flat neuron (b*512+o)
    const int g   = g0 + tid;
    const int b   = g >> 9, o = g & 511;
    const float* p = O + (size_t)b * 256 * 512 + o; // stride 512 per t

    float a[32], bb[32];
#pragma unroll
    for (int u = 0; u < 32; ++u) a[u] = p[(size_t)u * 512];
    float I = 0.f, V = 0.f, carry = 0.f;

    const int tq  = tid & 7;
    const int lnb = tid >> 3;

    auto flush = [&](int tt0) {
        __syncthreads();
#pragma unroll
        for (int gq = 0; gq < 8; ++gq) {
            int ln = lnb + gq * 32;
            float4 v;
            v.x = tileS[tq * 4 + 0][ln];
            v.y = tileS[tq * 4 + 1][ln];
            v.z = tileS[tq * 4 + 2][ln];
            v.w = tileS[tq * 4 + 3][ln];
            *(float4*)&out[(size_t)(g0 + ln) * 256 + tt0 + tq * 4] = v;
        }
        __syncthreads();
    };

    for (int t = 0; t < 256; t += 64) {
#pragma unroll
        for (int u = 0; u < 32; ++u) bb[u] = p[(size_t)(t + 32 + u) * 512];
        tileS[0][tid] = carry;
#pragma unroll
        for (int u = 0; u < 32; ++u) {
            I = floorf(I * 0.75f) + 64.f * a[u];
            V = floorf(V * 0.96875f) + I;
            float s = (V >= 5120.f) ? 1.f : 0.f;
            V *= (1.f - s);
            if (u < 31) tileS[u + 1][tid] = s; else carry = s;
        }
        flush(t);
        if (t + 64 < 256) {
#pragma unroll
            for (int u = 0; u < 32; ++u) a[u] = p[(size_t)(t + 64 + u) * 512];
        }
        tileS[0][tid] = carry;
#pragma unroll
        for (int u = 0; u < 32; ++u) {
            I = floorf(I * 0.75f) + 64.f * bb[u];
            V = floorf(V * 0.96875f) + I;
            float s = (V >= 5120.f) ? 1.f : 0.f;
            V *= (1.f - s);
            if (u < 31) tileS[u + 1][tid] = s; else carry = s;
        }
        flush(t + 32);
    }
}

extern "C" void kernel_launch(void* const* d_in, const int* in_sizes, int n_in,
                              void* d_out, int out_size, void* d_ws, size_t ws_size,
                              hipStream_t stream) {
    const int B = 32, IN = 1024, HID = 2048, OUT = 512, T = 256;
    const float* spikes = (const float*)d_in[0];
    const float* W1 = (const float*)d_in[1];
    const float* W2 = (const float*)d_in[2];
    float* out = (float*)d_out;

    char* ws = (char*)d_ws;
    size_t off = 0;
    auto alloc = [&](size_t bytes) -> void* {
        void* p = ws + off;
        off += (bytes + 255) & ~(size_t)255;
        return p;
    };
    i8*    Xb  = (i8*)   alloc((size_t)B * T * IN);         // [B,T,IN] i8 0/1
    i8*    W1q = (i8*)   alloc((size_t)HID * IN);           // [HID,IN] i8 = w/2
    i8*    W2q = (i8*)   alloc((size_t)OUT * HID);          // [OUT,HID] i8 = w/2
    i8*    S1  = (i8*)   alloc((size_t)B * T * HID);        // [B,T,HID] i8 (shifted)
    float* O   = (float*)alloc((size_t)B * T * OUT * 4);    // [B,T,OUT] f32 exact

    dim3 blk(256);
    transpose_x_bt<<<dim3(T / 32, IN / 128, B), blk, 0, stream>>>(spikes, Xb, B, IN, T);
    {
        int n1v = HID * IN / 4, n2v = OUT * HID / 4;
        quant_both<<<dim3((n1v + n2v + 255) / 256), blk, 0, stream>>>(
            (const float4*)W1, (const float4*)W2, (char4*)W1q, (char4*)W2q, n1v, n2v);
    }
    // fused GEMM1 + scan1: 32 b x 32 n-tiles = 1024 wgs (%8==0 for swizzle)
    gemm1_scan1<<<dim3(1024), blk, 0, stream>>>(Xb, W1q, S1, IN);
    {   // GEMM2: [8192,2048]i8 x [512,2048]i8^T -> O f32 ; 4x64=256 wgs
        int nbx = OUT / 128, nby = (T * B) / 128;
        gemm2_i8<<<dim3(nbx * nby), blk, 0, stream>>>(S1, W2q, O, T * B, OUT, HID, nbx);
    }
    scan2_fused<<<dim3(B * OUT / 256), blk, 0, stream>>>(O, out);
}

// Round 8
// 75.467 us; speedup vs baseline: 1.3202x; 1.0747x over previous
//
#include <hip/hip_runtime.h>

typedef unsigned char u8;
typedef signed char i8;
typedef unsigned int u32;
typedef __attribute__((ext_vector_type(4))) int i32x4;

#define AS1 __attribute__((address_space(1)))
#define AS3 __attribute__((address_space(3)))

__device__ __forceinline__ void gload_lds16(const void* g, void* l) {
    __builtin_amdgcn_global_load_lds((const AS1 void*)g, (AS3 void*)l, 16, 0, 0);
}

// ---------- transpose [B, IN, T] f32 -> [B, T, IN] i8 (0/1) ------------------
__global__ void transpose_x_bt(const float* __restrict__ X, i8* __restrict__ Xb,
                               int B, int IN, int T) {
    __shared__ float tile[128][33];          // [i_loc][t_loc]
    const int t0 = blockIdx.x * 32, i0 = blockIdx.y * 128, b = blockIdx.z;
    const int tx = threadIdx.x & 31, ty = threadIdx.x >> 5;
    const float* src = X + (size_t)b * IN * T;
#pragma unroll
    for (int r = 0; r < 16; ++r) {
        int i = ty + r * 8;
        tile[i][tx] = src[(size_t)(i0 + i) * T + t0 + tx];
    }
    __syncthreads();
    const int cx = threadIdx.x & 31;         // 4-i chunk within 128
    const int tl0 = threadIdx.x >> 5;
#pragma unroll
    for (int r = 0; r < 4; ++r) {
        int tl = tl0 + r * 8;
        uchar4 pk;
        pk.x = (tile[cx * 4 + 0][tl] != 0.f) ? 1 : 0;
        pk.y = (tile[cx * 4 + 1][tl] != 0.f) ? 1 : 0;
        pk.z = (tile[cx * 4 + 2][tl] != 0.f) ? 1 : 0;
        pk.w = (tile[cx * 4 + 3][tl] != 0.f) ? 1 : 0;
        *(uchar4*)&Xb[((size_t)b * T + t0 + tl) * IN + i0 + cx * 4] = pk;
    }
}

// ---------- quantize both W: w -> i8( round_half_even(w/2) ), float4 ---------
__global__ void quant_both(const float4* __restrict__ W1, const float4* __restrict__ W2,
                           char4* __restrict__ W1q, char4* __restrict__ W2q,
                           int n1v, int n2v) {
    int i = blockIdx.x * 256 + threadIdx.x;
    if (i < n1v) {
        float4 w = W1[i];
        char4 q;
        q.x = (i8)(int)rintf(w.x * 0.5f);
        q.y = (i8)(int)rintf(w.y * 0.5f);
        q.z = (i8)(int)rintf(w.z * 0.5f);
        q.w = (i8)(int)rintf(w.w * 0.5f);
        W1q[i] = q;
    } else if (i < n1v + n2v) {
        int j = i - n1v;
        float4 w = W2[j];
        char4 q;
        q.x = (i8)(int)rintf(w.x * 0.5f);
        q.y = (i8)(int)rintf(w.y * 0.5f);
        q.z = (i8)(int)rintf(w.z * 0.5f);
        q.w = (i8)(int)rintf(w.w * 0.5f);
        W2q[j] = q;
    }
}

// ---------- FUSED GEMM1 + Loihi scan1 ----------------------------------------
// A = Xb [B*T, 1024] i8 (b-major rows), Bt = W1q [2048, 1024] i8.
// Block: 256x64 tile = all 256 timesteps of batch `by` x 64 neurons.
// Scan wave chosen per-block via (blockIdx>>3)&3 so co-resident blocks scan
// on DIFFERENT SIMDs (wave i -> SIMD i). 40960 B LDS = exactly 4 blocks/CU.
__global__ __launch_bounds__(256, 4) void gemm1_scan1(
        const i8* __restrict__ A, const i8* __restrict__ Bt,
        i8* __restrict__ S1, int K) {
    __shared__ __align__(16) i8 lds[40960];
    i8*    lA   = lds;                        // 256x128 staging  (32 KB)
    i8*    lB   = lds + 32768;                // 64x128 staging   (8 KB)
    short* hT   = (short*)lds;                // [64 n][256 t] i16 (aliases lA)
    u32*   bits = (u32*)(lds + 32768);        // [8 w][64 n]       (aliases lB)

    const int nwg = gridDim.x;                // 1024, %8==0
    const int cpx = nwg >> 3;
    const int wg  = (blockIdx.x & 7) * cpx + (blockIdx.x >> 3);
    const int scanw = (blockIdx.x >> 3) & 3;  // co-resident blocks -> diff SIMDs
    const int bx = wg & 31;                   // neuron tile (32 of 64)
    const int by = wg >> 5;                   // batch element (32)
    const int n0 = bx * 64;
    const int m0 = by * 256;

    const int tid  = threadIdx.x;
    const int lane = tid & 63;
    const int w    = tid >> 6;                // wave = M-quadrant (64 rows)
    const int l15 = lane & 15;
    const int l4  = lane >> 4;
    const int sw  = l15 & 7;

    i32x4 acc[4][4] = {};
    const int flatT = tid * 16;

    for (int k0 = 0; k0 < K; k0 += 128) {
        __syncthreads();
#pragma unroll
        for (int q = 0; q < 8; ++q) {         // A: 32 KB
            int fl = q * 4096 + flatT;
            int r  = fl >> 7;
            int sc = ((fl >> 4) & 7) ^ (r & 7);
            gload_lds16(A + (size_t)(m0 + r) * K + k0 + sc * 16, &lA[fl]);
        }
#pragma unroll
        for (int q = 0; q < 2; ++q) {         // B: 8 KB
            int fl = q * 4096 + flatT;
            int r  = fl >> 7;
            int sc = ((fl >> 4) & 7) ^ (r & 7);
            gload_lds16(Bt + (size_t)(n0 + r) * K + k0 + sc * 16, &lB[fl]);
        }
        __syncthreads();
#pragma unroll
        for (int kk = 0; kk < 2; ++kk) {
            i32x4 af[4], bf[4];
#pragma unroll
            for (int mf = 0; mf < 4; ++mf)
                af[mf] = *(const i32x4*)&lA[(w * 64 + mf * 16 + l15) * 128 +
                                            ((kk * 4 + l4) ^ sw) * 16];
#pragma unroll
            for (int nf = 0; nf < 4; ++nf)
                bf[nf] = *(const i32x4*)&lB[(nf * 16 + l15) * 128 +
                                            ((kk * 4 + l4) ^ sw) * 16];
#pragma unroll
            for (int mf = 0; mf < 4; ++mf)
#pragma unroll
                for (int nf = 0; nf < 4; ++nf)
                    acc[mf][nf] = __builtin_amdgcn_mfma_i32_16x16x64_i8(
                        af[mf], bf[nf], acc[mf][nf], 0, 0, 0);
        }
    }
    __syncthreads();                          // staging LDS dead; reuse as hT

    // ---- phase 2: acc -> hT[n][t] i16, swizzled b64 chunk writes ------------
#pragma unroll
    for (int mf = 0; mf < 4; ++mf)
#pragma unroll
        for (int nf = 0; nf < 4; ++nf) {
            int n = nf * 16 + l15;
            int c = w * 16 + mf * 4 + l4;     // t-chunk (4 t's)
            int h0 = acc[mf][nf][0] * 2, h1 = acc[mf][nf][1] * 2;
            int h2 = acc[mf][nf][2] * 2, h3 = acc[mf][nf][3] * 2;
            int2 pk;
            pk.x = (h0 & 0xffff) | (h1 << 16);
            pk.y = (h2 & 0xffff) | (h3 << 16);
            *(int2*)((char*)hT + n * 512 + ((c ^ (n & 15)) << 3)) = pk;
        }
    __syncthreads();

    // ---- phase 3: one wave (scanw) scans 64 neurons -------------------------
    if (w == scanw) {
        const int n = lane;
        const int nx = n & 15;
        const char* hrow = (char*)hT + n * 512;
        int2 ra[4], rb[4];
#pragma unroll
        for (int q = 0; q < 4; ++q)
            ra[q] = *(const int2*)(hrow + ((q ^ nx) << 3));
        u32 bw[8] = {0, 0, 0, 0, 0, 0, 0, 0};
        float I = 0.f, V = 0.f;
#pragma unroll
        for (int p = 0; p < 16; ++p) {        // 16 phases x 16 t
            if (p < 15) {
#pragma unroll
                for (int q = 0; q < 4; ++q) {
                    int2 v = *(const int2*)(hrow + ((((p + 1) * 4 + q) ^ nx) << 3));
                    if (p & 1) ra[q] = v; else rb[q] = v;
                }
            }
#pragma unroll
            for (int q = 0; q < 4; ++q) {
                int2 hh = (p & 1) ? rb[q] : ra[q];
#pragma unroll
                for (int j = 0; j < 4; ++j) {
                    int t = p * 16 + q * 4 + j;
                    short hv = (j == 0) ? (short)hh.x
                             : (j == 1) ? (short)(hh.x >> 16)
                             : (j == 2) ? (short)hh.y
                                        : (short)(hh.y >> 16);
                    I = floorf(I * 0.75f) + 64.f * (float)hv;
                    V = floorf(V * 0.96875f) + I;
                    if (V >= 5120.f) { bw[t >> 5] |= (1u << (t & 31)); V = 0.f; }
                }
            }
        }
#pragma unroll
        for (int wi = 0; wi < 8; ++wi) bits[wi * 64 + n] = bw[wi];
    }
    __syncthreads();

    // ---- phase 4: delay-shifted spike write, coalesced dwords ---------------
#pragma unroll
    for (int rep = 0; rep < 16; ++rep) {
        int d   = rep * 256 + tid;            // 0..4095 = 256 rows x 16 dwords
        int tt  = d >> 4;                     // output timestep row
        int ndq = d & 15;                     // dword (4 neurons) within 64
        u32 outw = 0;
        if (tt > 0) {
            int tb = tt - 1, wi = tb >> 5, sh = tb & 31;
            outw =  ((bits[wi * 64 + ndq * 4 + 0] >> sh) & 1)
                 | (((bits[wi * 64 + ndq * 4 + 1] >> sh) & 1) << 8)
                 | (((bits[wi * 64 + ndq * 4 + 2] >> sh) & 1) << 16)
                 | (((bits[wi * 64 + ndq * 4 + 3] >> sh) & 1) << 24);
        }
        *(u32*)&S1[(size_t)(m0 + tt) * 2048 + n0 + ndq * 4] = outw;
    }
}

// ---------- FUSED GEMM2 + Loihi scan2 + output transpose ---------------------
// A = S1 [B*T, 2048] i8, Bt = W2q [512, 2048] i8.
// Block (by, ox): 256 t x 64 o. After GEMM, hT is f32 (layer-2 h can exceed
// i16). Scan wave -> bits; all threads write out[b][o][t] (delay-shifted).
__global__ __launch_bounds__(256, 1) void gemm2_scan2(
        const i8* __restrict__ A, const i8* __restrict__ Bt,
        float* __restrict__ out, int K) {
    __shared__ __align__(16) i8 lds[67584];
    i8*    lA   = lds;                        // 32 KB staging
    i8*    lB   = lds + 32768;                // 8 KB staging
    float* hT   = (float*)lds;                // [64 n][256 t] f32 = 64 KB (alias)
    u32*   bits = (u32*)(lds + 65536);        // 2 KB

    const int nwg = gridDim.x;                // 256, %8==0
    const int cpx = nwg >> 3;
    const int wg  = (blockIdx.x & 7) * cpx + (blockIdx.x >> 3);
    const int scanw = (blockIdx.x >> 3) & 3;
    const int ox = wg & 7;                    // 8 o-tiles of 64
    const int by = wg >> 3;                   // 32 batches
    const int n0 = ox * 64;
    const int m0 = by * 256;

    const int tid  = threadIdx.x;
    const int lane = tid & 63;
    const int w    = tid >> 6;
    const int l15 = lane & 15;
    const int l4  = lane >> 4;
    const int sw  = l15 & 7;

    i32x4 acc[4][4] = {};
    const int flatT = tid * 16;

    for (int k0 = 0; k0 < K; k0 += 128) {     // 16 K-steps
        __syncthreads();
#pragma unroll
        for (int q = 0; q < 8; ++q) {         // A: 32 KB
            int fl = q * 4096 + flatT;
            int r  = fl >> 7;
            int sc = ((fl >> 4) & 7) ^ (r & 7);
            gload_lds16(A + (size_t)(m0 + r) * K + k0 + sc * 16, &lA[fl]);
        }
#pragma unroll
        for (int q = 0; q < 2; ++q) {         // B: 8 KB
            int fl = q * 4096 + flatT;
            int r  = fl >> 7;
            int sc = ((fl >> 4) & 7) ^ (r & 7);
            gload_lds16(Bt + (size_t)(n0 + r) * K + k0 + sc * 16, &lB[fl]);
        }
        __syncthreads();
#pragma unroll
        for (int kk = 0; kk < 2; ++kk) {
            i32x4 af[4], bf[4];
#pragma unroll
            for (int mf = 0; mf < 4; ++mf)
                af[mf] = *(const i32x4*)&lA[(w * 64 + mf * 16 + l15) * 128 +
                                            ((kk * 4 + l4) ^ sw) * 16];
#pragma unroll
            for (int nf = 0; nf < 4; ++nf)
                bf[nf] = *(const i32x4*)&lB[(nf * 16 + l15) * 128 +
                                            ((kk * 4 + l4) ^ sw) * 16];
#pragma unroll
            for (int mf = 0; mf < 4; ++mf)
#pragma unroll
                for (int nf = 0; nf < 4; ++nf)
                    acc[mf][nf] = __builtin_amdgcn_mfma_i32_16x16x64_i8(
                        af[mf], bf[nf], acc[mf][nf], 0, 0, 0);
        }
    }
    __syncthreads();                          // staging dead; reuse as hT

    // ---- phase 2: acc*2 -> hT[n][t] f32, swizzled 16B (4-t) chunks ----------
#pragma unroll
    for (int mf = 0; mf < 4; ++mf)
#pragma unroll
        for (int nf = 0; nf < 4; ++nf) {
            int n = nf * 16 + l15;
            int c = w * 16 + mf * 4 + l4;     // t-chunk of 4 t (0..63)
            float4 pk;
            pk.x = (float)(acc[mf][nf][0] * 2);
            pk.y = (float)(acc[mf][nf][1] * 2);
            pk.z = (float)(acc[mf][nf][2] * 2);
            pk.w = (float)(acc[mf][nf][3] * 2);
            *(float4*)((char*)hT + n * 1024 + ((c ^ (n & 15)) << 4)) = pk;
        }
    __syncthreads();

    // ---- phase 3: one wave scans 64 neurons ---------------------------------
    if (w == scanw) {
        const int n = lane;
        const int nx = n & 15;
        const char* hrow = (char*)hT + n * 1024;
        float4 ra[4], rb[4];
#pragma unroll
        for (int q = 0; q < 4; ++q)
            ra[q] = *(const float4*)(hrow + ((q ^ nx) << 4));
        u32 bw[8] = {0, 0, 0, 0, 0, 0, 0, 0};
        float I = 0.f, V = 0.f;
#pragma unroll
        for (int p = 0; p < 16; ++p) {        // 16 phases x 16 t
            if (p < 15) {
#pragma unroll
                for (int q = 0; q < 4; ++q) {
                    float4 v = *(const float4*)(hrow + ((((p + 1) * 4 + q) ^ nx) << 4));
                    if (p & 1) ra[q] = v; else rb[q] = v;
                }
            }
#pragma unroll
            for (int q = 0; q < 4; ++q) {
                float4 hh = (p & 1) ? rb[q] : ra[q];
#pragma unroll
                for (int j = 0; j < 4; ++j) {
                    int t = p * 16 + q * 4 + j;
                    float hv = (j == 0) ? hh.x : (j == 1) ? hh.y
                             : (j == 2) ? hh.z : hh.w;
                    I = floorf(I * 0.75f) + 64.f * hv;
                    V = floorf(V * 0.96875f) + I;
                    if (V >= 5120.f) { bw[t >> 5] |= (1u << (t & 31)); V = 0.f; }
                }
            }
        }
#pragma unroll
        for (int wi = 0; wi < 8; ++wi) bits[wi * 64 + n] = bw[wi];
    }
    __syncthreads();

    // ---- phase 4: delay-shifted f32 spike write to out[b][o][t], coalesced --
#pragma unroll
    for (int rep = 0; rep < 16; ++rep) {
        int flat = rep * 256 + tid;           // 0..4095 = 64 o x 64 t-quads
        int o  = flat >> 6;                   // local neuron 0..63
        int t4 = flat & 63;                   // float4 index along t
        float4 v;
#pragma unroll
        for (int j = 0; j < 4; ++j) {
            int tt = t4 * 4 + j;
            float s = 0.f;
            if (tt > 0) {
                int tb = tt - 1;
                s = (float)((bits[(tb >> 5) * 64 + o] >> (tb & 31)) & 1);
            }
            if (j == 0) v.x = s; else if (j == 1) v.y = s;
            else if (j == 2) v.z = s; else v.w = s;
        }
        *(float4*)&out[((size_t)by * 512 + n0 + o) * 256 + t4 * 4] = v;
    }
}

extern "C" void kernel_launch(void* const* d_in, const int* in_sizes, int n_in,
                              void* d_out, int out_size, void* d_ws, size_t ws_size,
                              hipStream_t stream) {
    const int B = 32, IN = 1024, HID = 2048, OUT = 512, T = 256;
    const float* spikes = (const float*)d_in[0];
    const float* W1 = (const float*)d_in[1];
    const float* W2 = (const float*)d_in[2];
    float* out = (float*)d_out;

    char* ws = (char*)d_ws;
    size_t off = 0;
    auto alloc = [&](size_t bytes) -> void* {
        void* p = ws + off;
        off += (bytes + 255) & ~(size_t)255;
        return p;
    };
    i8* Xb  = (i8*)alloc((size_t)B * T * IN);      // [B,T,IN] i8 0/1
    i8* W1q = (i8*)alloc((size_t)HID * IN);        // [HID,IN] i8 = w/2
    i8* W2q = (i8*)alloc((size_t)OUT * HID);       // [OUT,HID] i8 = w/2
    i8* S1  = (i8*)alloc((size_t)B * T * HID);     // [B,T,HID] i8 (shifted)

    dim3 blk(256);
    transpose_x_bt<<<dim3(T / 32, IN / 128, B), blk, 0, stream>>>(spikes, Xb, B, IN, T);
    {
        int n1v = HID * IN / 4, n2v = OUT * HID / 4;
        quant_both<<<dim3((n1v + n2v + 255) / 256), blk, 0, stream>>>(
            (const float4*)W1, (const float4*)W2, (char4*)W1q, (char4*)W2q, n1v, n2v);
    }
    gemm1_scan1<<<dim3(1024), blk, 0, stream>>>(Xb, W1q, S1, IN);
    gemm2_scan2<<<dim3(256), blk, 0, stream>>>(S1, W2q, out, HID);
}

// Round 9
// 68.128 us; speedup vs baseline: 1.4624x; 1.1077x over previous
//
#include <hip/hip_runtime.h>

typedef unsigned char u8;
typedef signed char i8;
typedef unsigned int u32;
typedef __attribute__((ext_vector_type(4))) int i32x4;

#define AS1 __attribute__((address_space(1)))
#define AS3 __attribute__((address_space(3)))

__device__ __forceinline__ void gload_lds16(const void* g, void* l) {
    __builtin_amdgcn_global_load_lds((const AS1 void*)g, (AS3 void*)l, 16, 0, 0);
}

// ---------- transpose [B, IN, T] f32 -> [B, T, IN] i8 (0/1) ------------------
__global__ void transpose_x_bt(const float* __restrict__ X, i8* __restrict__ Xb,
                               int B, int IN, int T) {
    __shared__ float tile[128][33];          // [i_loc][t_loc]
    const int t0 = blockIdx.x * 32, i0 = blockIdx.y * 128, b = blockIdx.z;
    const int tx = threadIdx.x & 31, ty = threadIdx.x >> 5;
    const float* src = X + (size_t)b * IN * T;
#pragma unroll
    for (int r = 0; r < 16; ++r) {
        int i = ty + r * 8;
        tile[i][tx] = src[(size_t)(i0 + i) * T + t0 + tx];
    }
    __syncthreads();
    const int cx = threadIdx.x & 31;         // 4-i chunk within 128
    const int tl0 = threadIdx.x >> 5;
#pragma unroll
    for (int r = 0; r < 4; ++r) {
        int tl = tl0 + r * 8;
        uchar4 pk;
        pk.x = (tile[cx * 4 + 0][tl] != 0.f) ? 1 : 0;
        pk.y = (tile[cx * 4 + 1][tl] != 0.f) ? 1 : 0;
        pk.z = (tile[cx * 4 + 2][tl] != 0.f) ? 1 : 0;
        pk.w = (tile[cx * 4 + 3][tl] != 0.f) ? 1 : 0;
        *(uchar4*)&Xb[((size_t)b * T + t0 + tl) * IN + i0 + cx * 4] = pk;
    }
}

// ---------- quantize both W: w -> i8( round_half_even(w/2) ), float4 ---------
__global__ void quant_both(const float4* __restrict__ W1, const float4* __restrict__ W2,
                           char4* __restrict__ W1q, char4* __restrict__ W2q,
                           int n1v, int n2v) {
    int i = blockIdx.x * 256 + threadIdx.x;
    if (i < n1v) {
        float4 w = W1[i];
        char4 q;
        q.x = (i8)(int)rintf(w.x * 0.5f);
        q.y = (i8)(int)rintf(w.y * 0.5f);
        q.z = (i8)(int)rintf(w.z * 0.5f);
        q.w = (i8)(int)rintf(w.w * 0.5f);
        W1q[i] = q;
    } else if (i < n1v + n2v) {
        int j = i - n1v;
        float4 w = W2[j];
        char4 q;
        q.x = (i8)(int)rintf(w.x * 0.5f);
        q.y = (i8)(int)rintf(w.y * 0.5f);
        q.z = (i8)(int)rintf(w.z * 0.5f);
        q.w = (i8)(int)rintf(w.w * 0.5f);
        W2q[j] = q;
    }
}

// ---------- FUSED GEMM1 + Loihi scan1 (unchanged, proven) --------------------
__global__ __launch_bounds__(256, 4) void gemm1_scan1(
        const i8* __restrict__ A, const i8* __restrict__ Bt,
        i8* __restrict__ S1, int K) {
    __shared__ __align__(16) i8 lds[40960];
    i8*    lA   = lds;                        // 256x128 staging  (32 KB)
    i8*    lB   = lds + 32768;                // 64x128 staging   (8 KB)
    short* hT   = (short*)lds;                // [64 n][256 t] i16 (aliases lA)
    u32*   bits = (u32*)(lds + 32768);        // [8 w][64 n]       (aliases lB)

    const int nwg = gridDim.x;                // 1024, %8==0
    const int cpx = nwg >> 3;
    const int wg  = (blockIdx.x & 7) * cpx + (blockIdx.x >> 3);
    const int scanw = (blockIdx.x >> 3) & 3;  // co-resident blocks -> diff SIMDs
    const int bx = wg & 31;                   // neuron tile (32 of 64)
    const int by = wg >> 5;                   // batch element (32)
    const int n0 = bx * 64;
    const int m0 = by * 256;

    const int tid  = threadIdx.x;
    const int lane = tid & 63;
    const int w    = tid >> 6;                // wave = M-quadrant (64 rows)
    const int l15 = lane & 15;
    const int l4  = lane >> 4;
    const int sw  = l15 & 7;

    i32x4 acc[4][4] = {};
    const int flatT = tid * 16;

    for (int k0 = 0; k0 < K; k0 += 128) {
        __syncthreads();
#pragma unroll
        for (int q = 0; q < 8; ++q) {         // A: 32 KB
            int fl = q * 4096 + flatT;
            int r  = fl >> 7;
            int sc = ((fl >> 4) & 7) ^ (r & 7);
            gload_lds16(A + (size_t)(m0 + r) * K + k0 + sc * 16, &lA[fl]);
        }
#pragma unroll
        for (int q = 0; q < 2; ++q) {         // B: 8 KB
            int fl = q * 4096 + flatT;
            int r  = fl >> 7;
            int sc = ((fl >> 4) & 7) ^ (r & 7);
            gload_lds16(Bt + (size_t)(n0 + r) * K + k0 + sc * 16, &lB[fl]);
        }
        __syncthreads();
#pragma unroll
        for (int kk = 0; kk < 2; ++kk) {
            i32x4 af[4], bf[4];
#pragma unroll
            for (int mf = 0; mf < 4; ++mf)
                af[mf] = *(const i32x4*)&lA[(w * 64 + mf * 16 + l15) * 128 +
                                            ((kk * 4 + l4) ^ sw) * 16];
#pragma unroll
            for (int nf = 0; nf < 4; ++nf)
                bf[nf] = *(const i32x4*)&lB[(nf * 16 + l15) * 128 +
                                            ((kk * 4 + l4) ^ sw) * 16];
#pragma unroll
            for (int mf = 0; mf < 4; ++mf)
#pragma unroll
                for (int nf = 0; nf < 4; ++nf)
                    acc[mf][nf] = __builtin_amdgcn_mfma_i32_16x16x64_i8(
                        af[mf], bf[nf], acc[mf][nf], 0, 0, 0);
        }
    }
    __syncthreads();                          // staging LDS dead; reuse as hT

#pragma unroll
    for (int mf = 0; mf < 4; ++mf)
#pragma unroll
        for (int nf = 0; nf < 4; ++nf) {
            int n = nf * 16 + l15;
            int c = w * 16 + mf * 4 + l4;     // t-chunk (4 t's)
            int h0 = acc[mf][nf][0] * 2, h1 = acc[mf][nf][1] * 2;
            int h2 = acc[mf][nf][2] * 2, h3 = acc[mf][nf][3] * 2;
            int2 pk;
            pk.x = (h0 & 0xffff) | (h1 << 16);
            pk.y = (h2 & 0xffff) | (h3 << 16);
            *(int2*)((char*)hT + n * 512 + ((c ^ (n & 15)) << 3)) = pk;
        }
    __syncthreads();

    if (w == scanw) {
        const int n = lane;
        const int nx = n & 15;
        const char* hrow = (char*)hT + n * 512;
        int2 ra[4], rb[4];
#pragma unroll
        for (int q = 0; q < 4; ++q)
            ra[q] = *(const int2*)(hrow + ((q ^ nx) << 3));
        u32 bw[8] = {0, 0, 0, 0, 0, 0, 0, 0};
        float I = 0.f, V = 0.f;
#pragma unroll
        for (int p = 0; p < 16; ++p) {        // 16 phases x 16 t
            if (p < 15) {
#pragma unroll
                for (int q = 0; q < 4; ++q) {
                    int2 v = *(const int2*)(hrow + ((((p + 1) * 4 + q) ^ nx) << 3));
                    if (p & 1) ra[q] = v; else rb[q] = v;
                }
            }
#pragma unroll
            for (int q = 0; q < 4; ++q) {
                int2 hh = (p & 1) ? rb[q] : ra[q];
#pragma unroll
                for (int j = 0; j < 4; ++j) {
                    int t = p * 16 + q * 4 + j;
                    short hv = (j == 0) ? (short)hh.x
                             : (j == 1) ? (short)(hh.x >> 16)
                             : (j == 2) ? (short)hh.y
                                        : (short)(hh.y >> 16);
                    I = floorf(I * 0.75f) + 64.f * (float)hv;
                    V = floorf(V * 0.96875f) + I;
                    if (V >= 5120.f) { bw[t >> 5] |= (1u << (t & 31)); V = 0.f; }
                }
            }
        }
#pragma unroll
        for (int wi = 0; wi < 8; ++wi) bits[wi * 64 + n] = bw[wi];
    }
    __syncthreads();

#pragma unroll
    for (int rep = 0; rep < 16; ++rep) {
        int d   = rep * 256 + tid;            // 0..4095 = 256 rows x 16 dwords
        int tt  = d >> 4;
        int ndq = d & 15;
        u32 outw = 0;
        if (tt > 0) {
            int tb = tt - 1, wi = tb >> 5, sh = tb & 31;
            outw =  ((bits[wi * 64 + ndq * 4 + 0] >> sh) & 1)
                 | (((bits[wi * 64 + ndq * 4 + 1] >> sh) & 1) << 8)
                 | (((bits[wi * 64 + ndq * 4 + 2] >> sh) & 1) << 16)
                 | (((bits[wi * 64 + ndq * 4 + 3] >> sh) & 1) << 24);
        }
        *(u32*)&S1[(size_t)(m0 + tt) * 2048 + n0 + ndq * 4] = outw;
    }
}

// ---------- FUSED GEMM2 + scan2 + output transpose, v2: 1024 thr, dbuf -------
// 256 blocks (1/CU is forced by scan locality) but 16 waves/block = 4/SIMD
// issue parallelism + double-buffered staging. Wave w owns rows w*16..w*16+15.
// LDS: dbuf staging 2x(32K A + 8K B) = 80 KB; hT f32 64 KB aliases staging;
// bits 2 KB at 80 KB. Total 82 KB -> 1 block/CU.
__global__ __launch_bounds__(1024, 1) void gemm2_scan2(
        const i8* __restrict__ A, const i8* __restrict__ Bt,
        float* __restrict__ out, int K) {
    __shared__ __align__(16) i8 lds[83968];
    float* hT   = (float*)lds;                // [64 n][256 t] f32 (alias staging)
    u32*   bits = (u32*)(lds + 81920);        // 2 KB

    const int nwg = gridDim.x;                // 256, %8==0
    const int cpx = nwg >> 3;
    const int wg  = (blockIdx.x & 7) * cpx + (blockIdx.x >> 3);
    const int scanw = (blockIdx.x >> 3) & 15;
    const int ox = wg & 7;                    // 8 o-tiles of 64
    const int by = wg >> 3;                   // 32 batches
    const int n0 = ox * 64;
    const int m0 = by * 256;

    const int tid  = threadIdx.x;
    const int lane = tid & 63;
    const int w    = tid >> 6;                // 0..15, rows w*16..w*16+15
    const int l15 = lane & 15;
    const int l4  = lane >> 4;
    const int sw  = l15 & 7;

    i32x4 acc[4] = {};                        // N=64: 4 frags of 16x16
    const int flatT = tid * 16;

    // buf offsets: lA at buf*40960, lB at buf*40960 + 32768
    auto STAGE = [&](int buf, int k0) {
        i8* lA = lds + buf * 40960;
        i8* lB = lA + 32768;
#pragma unroll
        for (int q = 0; q < 2; ++q) {         // A: 32 KB over 1024 thr
            int fl = q * 16384 + flatT;
            int r  = fl >> 7;
            int sc = ((fl >> 4) & 7) ^ (r & 7);
            gload_lds16(A + (size_t)(m0 + r) * K + k0 + sc * 16, &lA[fl]);
        }
        if (tid < 512) {                      // B: 8 KB over 512 thr
            int fl = flatT;
            int r  = fl >> 7;
            int sc = ((fl >> 4) & 7) ^ (r & 7);
            gload_lds16(Bt + (size_t)(n0 + r) * K + k0 + sc * 16, &lB[fl]);
        }
    };

    auto COMPUTE = [&](int buf) {
        const i8* lA = lds + buf * 40960;
        const i8* lB = lA + 32768;
#pragma unroll
        for (int kk = 0; kk < 2; ++kk) {
            i32x4 af, bf[4];
            af = *(const i32x4*)&lA[(w * 16 + l15) * 128 + ((kk * 4 + l4) ^ sw) * 16];
#pragma unroll
            for (int nf = 0; nf < 4; ++nf)
                bf[nf] = *(const i32x4*)&lB[(nf * 16 + l15) * 128 +
                                            ((kk * 4 + l4) ^ sw) * 16];
#pragma unroll
            for (int nf = 0; nf < 4; ++nf)
                acc[nf] = __builtin_amdgcn_mfma_i32_16x16x64_i8(
                    af, bf[nf], acc[nf], 0, 0, 0);
        }
    };

    STAGE(0, 0);
    __syncthreads();                          // tile 0 landed
    int cur = 0;
    for (int k0 = 0; k0 < K; k0 += 128) {     // 16 K-steps
        if (k0 + 128 < K) STAGE(cur ^ 1, k0 + 128);
        COMPUTE(cur);
        __syncthreads();                      // prefetch landed; readers done
        cur ^= 1;
    }

    // ---- phase 2: acc*2 -> hT[n][t] f32, swizzled 16B (4-t) chunks ----------
    // lane's rows = w*16 + l4*4 + j (4 consecutive t) -> chunk c = w*4 + l4
#pragma unroll
    for (int nf = 0; nf < 4; ++nf) {
        int n = nf * 16 + l15;
        int c = w * 4 + l4;                   // t-chunk 0..63
        float4 pk;
        pk.x = (float)(acc[nf][0] * 2);
        pk.y = (float)(acc[nf][1] * 2);
        pk.z = (float)(acc[nf][2] * 2);
        pk.w = (float)(acc[nf][3] * 2);
        *(float4*)((char*)hT + n * 1024 + ((c ^ (n & 15)) << 4)) = pk;
    }
    __syncthreads();

    // ---- phase 3: one wave scans 64 neurons ---------------------------------
    if (w == scanw) {
        const int n = lane;
        const int nx = n & 15;
        const char* hrow = (char*)hT + n * 1024;
        float4 ra[4], rb[4];
#pragma unroll
        for (int q = 0; q < 4; ++q)
            ra[q] = *(const float4*)(hrow + ((q ^ nx) << 4));
        u32 bw[8] = {0, 0, 0, 0, 0, 0, 0, 0};
        float I = 0.f, V = 0.f;
#pragma unroll
        for (int p = 0; p < 16; ++p) {        // 16 phases x 16 t
            if (p < 15) {
#pragma unroll
                for (int q = 0; q < 4; ++q) {
                    float4 v = *(const float4*)(hrow + ((((p + 1) * 4 + q) ^ nx) << 4));
                    if (p & 1) ra[q] = v; else rb[q] = v;
                }
            }
#pragma unroll
            for (int q = 0; q < 4; ++q) {
                float4 hh = (p & 1) ? rb[q] : ra[q];
#pragma unroll
                for (int j = 0; j < 4; ++j) {
                    int t = p * 16 + q * 4 + j;
                    float hv = (j == 0) ? hh.x : (j == 1) ? hh.y
                             : (j == 2) ? hh.z : hh.w;
                    I = floorf(I * 0.75f) + 64.f * hv;
                    V = floorf(V * 0.96875f) + I;
                    if (V >= 5120.f) { bw[t >> 5] |= (1u << (t & 31)); V = 0.f; }
                }
            }
        }
#pragma unroll
        for (int wi = 0; wi < 8; ++wi) bits[wi * 64 + n] = bw[wi];
    }
    __syncthreads();

    // ---- phase 4: delay-shifted f32 spikes to out[b][o][t], coalesced -------
#pragma unroll
    for (int rep = 0; rep < 4; ++rep) {
        int flat = rep * 1024 + tid;          // 0..4095 = 64 o x 64 t-quads
        int o  = flat >> 6;
        int t4 = flat & 63;
        float4 v;
#pragma unroll
        for (int j = 0; j < 4; ++j) {
            int tt = t4 * 4 + j;
            float s = 0.f;
            if (tt > 0) {
                int tb = tt - 1;
                s = (float)((bits[(tb >> 5) * 64 + o] >> (tb & 31)) & 1);
            }
            if (j == 0) v.x = s; else if (j == 1) v.y = s;
            else if (j == 2) v.z = s; else v.w = s;
        }
        *(float4*)&out[((size_t)by * 512 + n0 + o) * 256 + t4 * 4] = v;
    }
}

extern "C" void kernel_launch(void* const* d_in, const int* in_sizes, int n_in,
                              void* d_out, int out_size, void* d_ws, size_t ws_size,
                              hipStream_t stream) {
    const int B = 32, IN = 1024, HID = 2048, OUT = 512, T = 256;
    const float* spikes = (const float*)d_in[0];
    const float* W1 = (const float*)d_in[1];
    const float* W2 = (const float*)d_in[2];
    float* out = (float*)d_out;

    char* ws = (char*)d_ws;
    size_t off = 0;
    auto alloc = [&](size_t bytes) -> void* {
        void* p = ws + off;
        off += (bytes + 255) & ~(size_t)255;
        return p;
    };
    i8* Xb  = (i8*)alloc((size_t)B * T * IN);      // [B,T,IN] i8 0/1
    i8* W1q = (i8*)alloc((size_t)HID * IN);        // [HID,IN] i8 = w/2
    i8* W2q = (i8*)alloc((size_t)OUT * HID);       // [OUT,HID] i8 = w/2
    i8* S1  = (i8*)alloc((size_t)B * T * HID);     // [B,T,HID] i8 (shifted)

    transpose_x_bt<<<dim3(T / 32, IN / 128, B), dim3(256), 0, stream>>>(spikes, Xb, B, IN, T);
    {
        int n1v = HID * IN / 4, n2v = OUT * HID / 4;
        quant_both<<<dim3((n1v + n2v + 255) / 256), dim3(256), 0, stream>>>(
            (const float4*)W1, (const float4*)W2, (char4*)W1q, (char4*)W2q, n1v, n2v);
    }
    gemm1_scan1<<<dim3(1024), dim3(256), 0, stream>>>(Xb, W1q, S1, IN);
    gemm2_scan2<<<dim3(256), dim3(1024), 0, stream>>>(S1, W2q, out, HID);
}